// Round 16
// baseline (254.234 us; speedup 1.0000x reference)
//
#include <hip/hip_runtime.h>

typedef __attribute__((ext_vector_type(4))) float f32x4;
typedef __attribute__((ext_vector_type(8))) short bf16x8;
typedef __attribute__((ext_vector_type(2))) uint u32x2;

#define SCALE_ 0.17677669529663687f

__device__ __forceinline__ float bf2f(ushort u){
  union { unsigned i; float f; } v; v.i = ((unsigned)u) << 16; return v.f;
}
__device__ __forceinline__ ushort f2bf(float f){
  union { float f; unsigned i; } v; v.f = f;
  unsigned r = v.i + 0x7fffu + ((v.i >> 16) & 1u);
  return (ushort)(r >> 16);
}
__device__ __forceinline__ void gl16(const void* g, const ushort* l) {
  __builtin_amdgcn_global_load_lds((const __attribute__((address_space(1))) uint*)g,
                                   (__attribute__((address_space(3))) uint*)l, 16, 0, 0);
}

// ---------------------------------------------------------------- prep (float4-vectorized) + wprep tail
__global__ __launch_bounds__(256) void k_prep(const float* __restrict__ x,
    const float* __restrict__ gt, const float* __restrict__ qw,
    const float* __restrict__ kvw, const float* __restrict__ pw,
    const float* __restrict__ srw, ushort* __restrict__ xc,
    ushort* __restrict__ xkv, float* __restrict__ out2,
    ushort* __restrict__ wq, ushort* __restrict__ wkv,
    ushort* __restrict__ wpr, ushort* __restrict__ wcv)
{
  int blk = blockIdx.x;
  int tid = threadIdx.x;
  if (blk >= 16640) {                       // wprep role
    int i = (blk - 16640) * 256 + tid;      // 0..524287
    if (i < 65536)            wq[i] = f2bf(qw[i]);
    else if (i < 196608)      wkv[i - 65536] = f2bf(kvw[i - 65536]);
    else if (i < 262144)      wpr[i - 196608] = f2bf(pw[i - 196608]);
    else {
      int j = i - 262144;
      int o = j >> 10, t = (j >> 8) & 3, cc = j & 255;
      wcv[j] = f2bf(srw[o * 1024 + cc * 4 + t]);
    }
    return;
  }
  int row = blk * 4 + (tid >> 6);           // 0..66559
  int c4 = (tid & 63) * 4;
  int wi = row / 65, n = row - wi * 65;
  if (n == 0) {
    float4 g4 = *(const float4*)(gt + (size_t)wi * 256 + c4);
    uint lo = (uint)f2bf(g4.x) | ((uint)f2bf(g4.y) << 16);
    uint hi = (uint)f2bf(g4.z) | ((uint)f2bf(g4.w) << 16);
    u32x2 pk = {lo, hi};
    *(u32x2*)(xc  + (size_t)row * 256 + c4) = pk;
    *(u32x2*)(xkv + (size_t)row * 256 + c4) = pk;
    *(float4*)(out2 + (size_t)wi * 256 + c4) = g4;
  } else {
    int s = n - 1, r = s >> 3, cc = s & 7;
    int b = wi >> 8, wh = (wi >> 4) & 15, ww = wi & 15;
    int hw = (wh * 8 + r) * 128 + ww * 8 + cc;
    float4 v4 = *(const float4*)(x + ((size_t)b * 16384 + hw) * 256 + c4);
    uint lo = (uint)f2bf(v4.x) | ((uint)f2bf(v4.y) << 16);
    uint hi = (uint)f2bf(v4.z) | ((uint)f2bf(v4.w) << 16);
    u32x2 pk = {lo, hi};
    *(u32x2*)(xc + (size_t)row * 256 + c4) = pk;
  }
}

// ---------------------------------------------------------------- tiled GEMM (m97 structure + XCD swizzle)
template<int N>
__global__ __launch_bounds__(256) void k_gemm2(const ushort* __restrict__ A,
    const ushort* __restrict__ W, const float* __restrict__ bias,
    ushort* __restrict__ C)
{
  constexpr int K = 256;
  __shared__ __align__(16) ushort As[2][128 * 64];
  __shared__ __align__(16) ushort Bs[2][128 * 64];
  int lin = blockIdx.y * gridDim.x + blockIdx.x;
  int qq = (gridDim.x * gridDim.y) >> 3;
  int sw2 = (lin & 7) * qq + (lin >> 3);
  int m0 = (sw2 / gridDim.x) * 128, n0 = (sw2 % gridDim.x) * 128;
  int tid = threadIdx.x, lane = tid & 63;
  int wave = tid >> 6;
  int lm = lane & 15, kg = lane >> 4;
  int wr = wave >> 1, wc = wave & 1;

  const char* Ab = (const char*)A + (size_t)m0 * (K * 2);
  const char* Bb = (const char*)W + (size_t)n0 * (K * 2);

  auto stage = [&](int buf, int kt) {
#pragma unroll
    for (int j = 0; j < 4; ++j) {
      int c = j * 256 + tid;            // chunk 0..1023
      int row = c >> 3, slot = c & 7;   // 8 x 16B per 128B row
      int srcoff = row * (K * 2) + kt * 128 + ((slot * 16) ^ ((row & 7) << 4));
      gl16(Ab + srcoff, (const ushort*)((const char*)As[buf] + c * 16));
      gl16(Bb + srcoff, (const ushort*)((const char*)Bs[buf] + c * 16));
    }
  };

  f32x4 acc[4][4];
  f32x4 zero = {0.f, 0.f, 0.f, 0.f};
#pragma unroll
  for (int a = 0; a < 4; ++a)
#pragma unroll
    for (int b = 0; b < 4; ++b) acc[a][b] = zero;

  stage(0, 0);
  __syncthreads();
#pragma unroll
  for (int t = 0; t < 4; ++t) {
    int cur = t & 1;
    if (t < 3) stage(cur ^ 1, t + 1);
#pragma unroll
    for (int s = 0; s < 2; ++s) {
      int sw = (lm & 7) << 4;
      bf16x8 af[4], bw[4];
#pragma unroll
      for (int mi = 0; mi < 4; ++mi) {
        int row = wr * 64 + mi * 16 + lm;
        af[mi] = *(const bf16x8*)((const char*)As[cur] + row * 128 + ((s * 64 + kg * 16) ^ sw));
      }
#pragma unroll
      for (int ni = 0; ni < 4; ++ni) {
        int row = wc * 64 + ni * 16 + lm;
        bw[ni] = *(const bf16x8*)((const char*)Bs[cur] + row * 128 + ((s * 64 + kg * 16) ^ sw));
      }
#pragma unroll
      for (int mi = 0; mi < 4; ++mi)
#pragma unroll
        for (int ni = 0; ni < 4; ++ni)
          acc[mi][ni] = __builtin_amdgcn_mfma_f32_16x16x32_bf16(af[mi], bw[ni], acc[mi][ni], 0, 0, 0);
    }
    __syncthreads();
  }

  int rbase = m0 + wr * 64 + kg * 4;
#pragma unroll
  for (int ni = 0; ni < 4; ++ni) {
    int col = n0 + wc * 64 + ni * 16 + lm;
    float bv = bias[col];
#pragma unroll
    for (int mi = 0; mi < 4; ++mi) {
#pragma unroll
      for (int r = 0; r < 4; ++r)
        C[(size_t)(rbase + mi * 16 + r) * N + col] = f2bf(acc[mi][ni][r] + bv);
    }
  }
}

// ---------------------------------------------------------------- proj GEMM with fused scatter epilogue
__global__ __launch_bounds__(256) void k_gemm_out(const ushort* __restrict__ A,
    const ushort* __restrict__ W, const float* __restrict__ bias,
    float* __restrict__ out)
{
  constexpr int K = 256;
  __shared__ __align__(16) ushort As[2][128 * 64];
  __shared__ __align__(16) ushort Bs[2][128 * 64];
  int lin = blockIdx.y * gridDim.x + blockIdx.x;
  int qq = (gridDim.x * gridDim.y) >> 3;
  int sw2 = (lin & 7) * qq + (lin >> 3);
  int m0 = (sw2 / gridDim.x) * 128, n0 = (sw2 % gridDim.x) * 128;
  int tid = threadIdx.x, lane = tid & 63;
  int wave = tid >> 6;
  int lm = lane & 15, kg = lane >> 4;
  int wr = wave >> 1, wc = wave & 1;

  const char* Ab = (const char*)A + (size_t)m0 * (K * 2);
  const char* Bb = (const char*)W + (size_t)n0 * (K * 2);

  auto stage = [&](int buf, int kt) {
#pragma unroll
    for (int j = 0; j < 4; ++j) {
      int c = j * 256 + tid;
      int row = c >> 3, slot = c & 7;
      int srcoff = row * (K * 2) + kt * 128 + ((slot * 16) ^ ((row & 7) << 4));
      gl16(Ab + srcoff, (const ushort*)((const char*)As[buf] + c * 16));
      gl16(Bb + srcoff, (const ushort*)((const char*)Bs[buf] + c * 16));
    }
  };

  f32x4 acc[4][4];
  f32x4 zero = {0.f, 0.f, 0.f, 0.f};
#pragma unroll
  for (int a = 0; a < 4; ++a)
#pragma unroll
    for (int b = 0; b < 4; ++b) acc[a][b] = zero;

  stage(0, 0);
  __syncthreads();
#pragma unroll
  for (int t = 0; t < 4; ++t) {
    int cur = t & 1;
    if (t < 3) stage(cur ^ 1, t + 1);
#pragma unroll
    for (int s = 0; s < 2; ++s) {
      int sw = (lm & 7) << 4;
      bf16x8 af[4], bw[4];
#pragma unroll
      for (int mi = 0; mi < 4; ++mi) {
        int row = wr * 64 + mi * 16 + lm;
        af[mi] = *(const bf16x8*)((const char*)As[cur] + row * 128 + ((s * 64 + kg * 16) ^ sw));
      }
#pragma unroll
      for (int ni = 0; ni < 4; ++ni) {
        int row = wc * 64 + ni * 16 + lm;
        bw[ni] = *(const bf16x8*)((const char*)Bs[cur] + row * 128 + ((s * 64 + kg * 16) ^ sw));
      }
#pragma unroll
      for (int mi = 0; mi < 4; ++mi)
#pragma unroll
        for (int ni = 0; ni < 4; ++ni)
          acc[mi][ni] = __builtin_amdgcn_mfma_f32_16x16x32_bf16(af[mi], bw[ni], acc[mi][ni], 0, 0, 0);
    }
    __syncthreads();
  }

  int rbase = m0 + wr * 64 + kg * 4;
#pragma unroll
  for (int mi = 0; mi < 4; ++mi) {
#pragma unroll
    for (int r = 0; r < 4; ++r) {
      int g = rbase + mi * 16 + r;
      int wi2 = g / 65;
      int n = g - wi2 * 65;
      size_t dstrow;
      if (n == 0) {
        dstrow = (size_t)(16777216 >> 8) + wi2;         // gt_out row
      } else {
        int s = n - 1;
        int b = wi2 >> 8, wh = (wi2 >> 4) & 15, ww = wi2 & 15;
        int r2 = s >> 3, cc = s & 7;
        dstrow = (size_t)(b << 14) + (wh * 8 + r2) * 128 + ww * 8 + cc;
      }
      float* dst = out + dstrow * 256;
#pragma unroll
      for (int ni = 0; ni < 4; ++ni) {
        int col = n0 + wc * 64 + ni * 16 + lm;
        dst[col] = acc[mi][ni][r] + bias[col];
      }
    }
  }
}

// ---------------------------------------------------------------- SR conv v2: 256 threads / 4 waves / window,
// K-split sub-tiles (tap x channel-half, K=128), 32KB LDS dbuf -> 4 blocks/CU (quarter barrier scope).
// Wave owns full 64s x 64o (acc[4][4]); build: thread = (s = tid>>2, 32 ch), per-thread-const bilinear wts.
__global__ __launch_bounds__(256) void k_conv(const ushort* __restrict__ xc,
    const ushort* __restrict__ wconv, ushort* __restrict__ cconv)
{
  __shared__ __align__(16) ushort U2[2][64 * 128];   // 2 x 16KB sub-tile buffers
  int wi = blockIdx.x;
  int tid = threadIdx.x, wave = tid >> 6, lane = tid & 63;
  int lm = lane & 15, kg = lane >> 4;
  const ushort* src = xc + (size_t)(wi * 65 + 1) * 256;

  f32x4 acc[4][4];
  f32x4 zero = {0.f, 0.f, 0.f, 0.f};
#pragma unroll
  for (int a = 0; a < 4; a++)
#pragma unroll
    for (int b = 0; b < 4; b++) acc[a][b] = zero;

  // build thread mapping: s = tid>>2 (per-thread constant), channel quad cq = tid&3 (32 ch)
  int bs = tid >> 2, cq = tid & 3;
  int bi = bs >> 3, bj = bs & 7;
  float py = (2 * bi) * (7.0f / 15.0f);           // dy added per tap
  float px = (2 * bj) * (7.0f / 15.0f);

  auto build = [&](int st, ushort* Ub) {          // st: sub-tile 0..7; tap = st>>1, chalf = st&1
    int t = st >> 1, h = st & 1;
    int dy = t >> 1, dx = t & 1;
    float pyt = py + dy * (7.0f / 15.0f);
    float pxt = px + dx * (7.0f / 15.0f);
    int iy = (int)pyt; if (iy > 6) iy = 6; float ty = pyt - iy;
    int ix = (int)pxt; if (ix > 6) ix = 6; float tx = pxt - ix;
    float w00 = (1.f - ty) * (1.f - tx), w01 = (1.f - ty) * tx;
    float w10 = ty * (1.f - tx), w11 = ty * tx;
    const ushort* p = src + (size_t)(iy * 8 + ix) * 256 + h * 128 + cq * 32;
#pragma unroll
    for (int j = 0; j < 4; ++j) {                 // 4 x 8 channels
      bf16x8 p00 = *(const bf16x8*)(p + j * 8);
      bf16x8 p01 = *(const bf16x8*)(p + j * 8 + 256);
      bf16x8 p10 = *(const bf16x8*)(p + j * 8 + 2048);
      bf16x8 p11 = *(const bf16x8*)(p + j * 8 + 2304);
      bf16x8 o8;
#pragma unroll
      for (int e = 0; e < 8; ++e) {
        float v = w00 * bf2f((ushort)p00[e]) + w01 * bf2f((ushort)p01[e])
                + w10 * bf2f((ushort)p10[e]) + w11 * bf2f((ushort)p11[e]);
        o8[e] = (short)f2bf(v);
      }
      int colb = (cq * 32 + j * 8) * 2;           // byte col in [0,256)
      int addr = bs * 256 + (colb ^ ((bs & 15) << 4));
      *(bf16x8*)((char*)Ub + addr) = o8;
    }
  };

  auto mfma_st = [&](int st, const ushort* Ub) {  // K=128 over this sub-tile
    int t = st >> 1, h = st & 1;
    const ushort* wc = wconv + t * 256 + h * 128;
#pragma unroll
    for (int kk = 0; kk < 128; kk += 32) {
      int colb = 2 * (kk + kg * 8);               // byte col in [0,256)
      bf16x8 afr[4];
#pragma unroll
      for (int mi = 0; mi < 4; mi++) {
        int srow = mi * 16 + lm;
        int addr = srow * 256 + (colb ^ ((srow & 15) << 4));
        afr[mi] = *(const bf16x8*)((const char*)Ub + addr);
      }
#pragma unroll
      for (int ni = 0; ni < 4; ni++) {
        bf16x8 b = *(const bf16x8*)(wc + (size_t)(wave * 64 + ni * 16 + lm) * 1024 + kk + kg * 8);
#pragma unroll
        for (int mi = 0; mi < 4; mi++)
          acc[mi][ni] = __builtin_amdgcn_mfma_f32_16x16x32_bf16(afr[mi], b, acc[mi][ni], 0, 0, 0);
      }
    }
  };

  build(0, U2[0]);
  __syncthreads();
  for (int st = 0; st < 8; ++st) {
    mfma_st(st, U2[st & 1]);
    if (st < 7) build(st + 1, U2[(st + 1) & 1]);
    __syncthreads();
  }

#pragma unroll
  for (int mi = 0; mi < 4; mi++) {
    int row = wi * 64 + mi * 16 + kg * 4;
#pragma unroll
    for (int ni = 0; ni < 4; ni++) {
      int col = wave * 64 + ni * 16 + lm;
#pragma unroll
      for (int r = 0; r < 4; r++)
        cconv[(size_t)(row + r) * 256 + col] = f2bf(acc[mi][ni][r]);
    }
  }
}

// ---------------------------------------------------------------- bias + LayerNorm (vectorized loads) -> xkv rows 1..64
__global__ __launch_bounds__(256) void k_ln(const ushort* __restrict__ cconv,
    const float* __restrict__ srb, const float* __restrict__ nw,
    const float* __restrict__ nb, ushort* __restrict__ xkv)
{
  int row = blockIdx.x * 4 + (threadIdx.x >> 6);   // 0..65535
  int lane = threadIdx.x & 63;
  int c0 = lane * 4;                               // 4 contiguous channels/thread
  u32x2 pk = *(const u32x2*)(cconv + (size_t)row * 256 + c0);
  float4 sb4 = *(const float4*)(srb + c0);
  float v0 = bf2f((ushort)(pk.x & 0xffffu)) + sb4.x;
  float v1 = bf2f((ushort)(pk.x >> 16))     + sb4.y;
  float v2 = bf2f((ushort)(pk.y & 0xffffu)) + sb4.z;
  float v3 = bf2f((ushort)(pk.y >> 16))     + sb4.w;
  float sum = v0 + v1 + v2 + v3;
  float sq  = v0 * v0 + v1 * v1 + v2 * v2 + v3 * v3;
#pragma unroll
  for (int off = 1; off < 64; off <<= 1) {
    sum += __shfl_xor(sum, off, 64);
    sq  += __shfl_xor(sq,  off, 64);
  }
  float mean = sum * (1.f / 256.f);
  float var = sq * (1.f / 256.f) - mean * mean;
  float rs = rsqrtf(var + 1e-5f);
  float4 nw4 = *(const float4*)(nw + c0);
  float4 nb4 = *(const float4*)(nb + c0);
  int wi = row >> 6, s = row & 63;
  ushort* o = xkv + (size_t)(wi * 65 + 1 + s) * 256 + c0;
  uint lo = (uint)f2bf((v0 - mean) * rs * nw4.x + nb4.x)
          | ((uint)f2bf((v1 - mean) * rs * nw4.y + nb4.y) << 16);
  uint hi = (uint)f2bf((v2 - mean) * rs * nw4.z + nb4.z)
          | ((uint)f2bf((v3 - mean) * rs * nw4.w + nb4.w) << 16);
  u32x2 opk = {lo, hi};
  *(u32x2*)o = opk;
}

// ---------------------------------------------------------------- MFMA attention: one wave per (window, head)
__global__ __launch_bounds__(256) void k_attn(const ushort* __restrict__ q,
    const ushort* __restrict__ kv, ushort* __restrict__ att)
{
  __shared__ ushort smem[4][8064];           // per wave: P [80][72] + V^T [32][72]
  int wi = blockIdx.x >> 1;
  int tid = threadIdx.x, wave = tid >> 6, lane = tid & 63;
  int h = (blockIdx.x & 1) * 4 + wave;
  int lm = lane & 15, kg = lane >> 4;
  ushort* plds = smem[wave];                 // [80][72] bf16 P (later reused for O)
  ushort* vt   = smem[wave] + 5760;          // [32][72] bf16 V^T

  size_t qbase  = (size_t)wi * 65 * 256 + (size_t)h * 32;
  size_t kvbase = (size_t)wi * 65 * 512 + (size_t)h * 32;

  for (int e = lane; e < 2080; e += 64) {
    int m = e >> 5, d = e & 31;
    vt[d * 72 + m] = kv[kvbase + (size_t)m * 512 + 256 + d];
  }

  bf16x8 akf[5], bqf[5];
#pragma unroll
  for (int i = 0; i < 5; i++) {
    akf[i] = *(const bf16x8*)(kv + kvbase + (size_t)(16 * i + lm) * 512 + kg * 8);
    bqf[i] = *(const bf16x8*)(q  + qbase  + (size_t)(16 * i + lm) * 256 + kg * 8);
  }

  f32x4 sc[5][5];
  f32x4 zero = {0.f, 0.f, 0.f, 0.f};
#pragma unroll
  for (int mi = 0; mi < 5; mi++)
#pragma unroll
    for (int nj = 0; nj < 5; nj++) sc[mi][nj] = zero;
#pragma unroll
  for (int mi = 0; mi < 5; mi++)
#pragma unroll
    for (int nj = 0; nj < 5; nj++)
      sc[mi][nj] = __builtin_amdgcn_mfma_f32_16x16x32_bf16(akf[mi], bqf[nj], sc[mi][nj], 0, 0, 0);

  const float C = SCALE_ * 1.4426950408889634f;   // scale * log2(e)
  float inv[5], p64b[5];
#pragma unroll
  for (int nj = 0; nj < 5; nj++) {
    float s4 = sc[4][nj][0];                      // m = 64+4*kg; valid only kg==0
    float mx = (kg == 0) ? s4 : -1e30f;
#pragma unroll
    for (int mi = 0; mi < 4; mi++)
#pragma unroll
      for (int r = 0; r < 4; r++) mx = fmaxf(mx, sc[mi][nj][r]);
    mx = fmaxf(mx, __shfl_xor(mx, 16, 64));
    mx = fmaxf(mx, __shfl_xor(mx, 32, 64));
    float sum = 0.f;
#pragma unroll
    for (int mi = 0; mi < 4; mi++)
#pragma unroll
      for (int r = 0; r < 4; r++) {
        float e = exp2f((sc[mi][nj][r] - mx) * C);
        sc[mi][nj][r] = e; sum += e;
      }
    float e4 = exp2f((s4 - mx) * C);
    sum += (kg == 0) ? e4 : 0.f;
    sum += __shfl_xor(sum, 16, 64);
    sum += __shfl_xor(sum, 32, 64);
    inv[nj] = 1.0f / sum;
    p64b[nj] = __shfl(e4, lm, 64);                // broadcast kg==0 value
  }

#pragma unroll
  for (int nj = 0; nj < 5; nj++) {
    int n = 16 * nj + lm;
#pragma unroll
    for (int mi = 0; mi < 4; mi++) {
      uint lo = (uint)f2bf(sc[mi][nj][0]) | ((uint)f2bf(sc[mi][nj][1]) << 16);
      uint hi = (uint)f2bf(sc[mi][nj][2]) | ((uint)f2bf(sc[mi][nj][3]) << 16);
      u32x2 pk = {lo, hi};
      *(u32x2*)(plds + n * 72 + 16 * mi + 4 * kg) = pk;
    }
  }

  f32x4 od[2][5];
#pragma unroll
  for (int dt = 0; dt < 2; dt++)
#pragma unroll
    for (int nj = 0; nj < 5; nj++) od[dt][nj] = zero;
#pragma unroll
  for (int c = 0; c < 2; c++) {
    bf16x8 av[2], bp[5];
#pragma unroll
    for (int dt = 0; dt < 2; dt++)
      av[dt] = *(const bf16x8*)(vt + (16 * dt + lm) * 72 + c * 32 + kg * 8);
#pragma unroll
    for (int nj = 0; nj < 5; nj++)
      bp[nj] = *(const bf16x8*)(plds + (16 * nj + lm) * 72 + c * 32 + kg * 8);
#pragma unroll
    for (int dt = 0; dt < 2; dt++)
#pragma unroll
      for (int nj = 0; nj < 5; nj++)
        od[dt][nj] = __builtin_amdgcn_mfma_f32_16x16x32_bf16(av[dt], bp[nj], od[dt][nj], 0, 0, 0);
  }
  float v64[8];
#pragma unroll
  for (int dt = 0; dt < 2; dt++)
#pragma unroll
    for (int r = 0; r < 4; r++)
      v64[dt * 4 + r] = bf2f(vt[(16 * dt + 4 * kg + r) * 72 + 64]);
#pragma unroll
  for (int dt = 0; dt < 2; dt++)
#pragma unroll
    for (int nj = 0; nj < 5; nj++)
#pragma unroll
      for (int r = 0; r < 4; r++)
        od[dt][nj][r] += v64[dt * 4 + r] * p64b[nj];

#pragma unroll
  for (int nj = 0; nj < 5; nj++) {
    int n = 16 * nj + lm;
    float scl = inv[nj];
#pragma unroll
    for (int dt = 0; dt < 2; dt++) {
      uint lo = (uint)f2bf(od[dt][nj][0] * scl) | ((uint)f2bf(od[dt][nj][1] * scl) << 16);
      uint hi = (uint)f2bf(od[dt][nj][2] * scl) | ((uint)f2bf(od[dt][nj][3] * scl) << 16);
      u32x2 pk = {lo, hi};
      *(u32x2*)(plds + n * 40 + 16 * dt + 4 * kg) = pk;
    }
  }
  size_t abase = (size_t)wi * 65 * 256 + (size_t)h * 32;
  for (int e = lane; e < 1040; e += 64) {
    int n = e >> 4, d2 = e & 15;
    *(uint*)(att + abase + (size_t)n * 256 + 2 * d2) = *(const uint*)(plds + n * 40 + 2 * d2);
  }
}

// ---------------------------------------------------------------- launch
extern "C" void kernel_launch(void* const* d_in, const int* in_sizes, int n_in,
                              void* d_out, int out_size, void* d_ws, size_t ws_size,
                              hipStream_t stream)
{
  const float* x    = (const float*)d_in[0];
  const float* gt   = (const float*)d_in[1];
  const float* q_w  = (const float*)d_in[2];
  const float* q_b  = (const float*)d_in[3];
  const float* kv_w = (const float*)d_in[4];
  const float* kv_b = (const float*)d_in[5];
  const float* sr_w = (const float*)d_in[6];
  const float* sr_b = (const float*)d_in[7];
  const float* nw   = (const float*)d_in[8];
  const float* nb   = (const float*)d_in[9];
  const float* p_w  = (const float*)d_in[10];
  const float* p_b  = (const float*)d_in[11];
  (void)in_sizes; (void)n_in; (void)out_size;

  if (ws_size < 204996608u) return;
  char* ws = (char*)d_ws;
  ushort* xc  = (ushort*)(ws);              // 34,078,720  (reused as att out)
  ushort* qb  = (ushort*)(ws + 34078720);   // 34,078,720  (Q-proj output)
  ushort* xkv = (ushort*)(ws + 68157440);   // 34,078,720
  ushort* kv  = (ushort*)(ws + 102236160);  // 68,157,440
  ushort* ccv = (ushort*)(ws + 170393600);  // 33,554,432
  ushort* wq  = (ushort*)(ws + 203948032);  // 131,072
  ushort* wkv = (ushort*)(ws + 204079104);  // 262,144
  ushort* wpr = (ushort*)(ws + 204341248);  // 131,072
  ushort* wcv = (ushort*)(ws + 204472320);  // 524,288

  float* out = (float*)d_out;
  float* out2 = out + 16777216 + 262144;    // skip

  k_prep<<<18688, 256, 0, stream>>>(x, gt, q_w, kv_w, p_w, sr_w,
                                    xc, xkv, out2, wq, wkv, wpr, wcv);
  k_gemm2<256><<<dim3(2, 520), 256, 0, stream>>>(xc, wq, q_b, qb);
  k_conv<<<1024, 256, 0, stream>>>(xc, wcv, ccv);
  k_ln<<<16384, 256, 0, stream>>>(ccv, sr_b, nw, nb, xkv);
  k_gemm2<512><<<dim3(4, 520), 256, 0, stream>>>(xkv, wkv, kv_b, kv);
  k_attn<<<2048, 256, 0, stream>>>(qb, kv, xc);
  k_gemm_out<<<dim3(2, 520), 256, 0, stream>>>(xc, wpr, p_b, out);
}

// Round 17
// 239.905 us; speedup vs baseline: 1.0597x; 1.0597x over previous
//
#include <hip/hip_runtime.h>

typedef __attribute__((ext_vector_type(4))) float f32x4;
typedef __attribute__((ext_vector_type(8))) float f32x8;
typedef __attribute__((ext_vector_type(8))) short bf16x8;
typedef __attribute__((ext_vector_type(2))) uint u32x2;

#define SCALE_ 0.17677669529663687f

__device__ __forceinline__ float bf2f(ushort u){
  union { unsigned i; float f; } v; v.i = ((unsigned)u) << 16; return v.f;
}
__device__ __forceinline__ ushort f2bf(float f){
  union { float f; unsigned i; } v; v.f = f;
  unsigned r = v.i + 0x7fffu + ((v.i >> 16) & 1u);
  return (ushort)(r >> 16);
}
__device__ __forceinline__ void gl16(const void* g, const ushort* l) {
  __builtin_amdgcn_global_load_lds((const __attribute__((address_space(1))) uint*)g,
                                   (__attribute__((address_space(3))) uint*)l, 16, 0, 0);
}

// ---------------------------------------------------------------- prep (float4-vectorized) + wprep tail
__global__ __launch_bounds__(256) void k_prep(const float* __restrict__ x,
    const float* __restrict__ gt, const float* __restrict__ qw,
    const float* __restrict__ kvw, const float* __restrict__ pw,
    const float* __restrict__ srw, ushort* __restrict__ xc,
    ushort* __restrict__ xkv, float* __restrict__ out2,
    ushort* __restrict__ wq, ushort* __restrict__ wkv,
    ushort* __restrict__ wpr, ushort* __restrict__ wcv)
{
  int blk = blockIdx.x;
  int tid = threadIdx.x;
  if (blk >= 16640) {                       // wprep role
    int i = (blk - 16640) * 256 + tid;      // 0..524287
    if (i < 65536)            wq[i] = f2bf(qw[i]);
    else if (i < 196608)      wkv[i - 65536] = f2bf(kvw[i - 65536]);
    else if (i < 262144)      wpr[i - 196608] = f2bf(pw[i - 196608]);
    else {
      int j = i - 262144;
      int o = j >> 10, t = (j >> 8) & 3, cc = j & 255;
      wcv[j] = f2bf(srw[o * 1024 + cc * 4 + t]);
    }
    return;
  }
  int row = blk * 4 + (tid >> 6);           // 0..66559
  int c4 = (tid & 63) * 4;
  int wi = row / 65, n = row - wi * 65;
  if (n == 0) {
    float4 g4 = *(const float4*)(gt + (size_t)wi * 256 + c4);
    uint lo = (uint)f2bf(g4.x) | ((uint)f2bf(g4.y) << 16);
    uint hi = (uint)f2bf(g4.z) | ((uint)f2bf(g4.w) << 16);
    u32x2 pk = {lo, hi};
    *(u32x2*)(xc  + (size_t)row * 256 + c4) = pk;
    *(u32x2*)(xkv + (size_t)row * 256 + c4) = pk;
    *(float4*)(out2 + (size_t)wi * 256 + c4) = g4;
  } else {
    int s = n - 1, r = s >> 3, cc = s & 7;
    int b = wi >> 8, wh = (wi >> 4) & 15, ww = wi & 15;
    int hw = (wh * 8 + r) * 128 + ww * 8 + cc;
    float4 v4 = *(const float4*)(x + ((size_t)b * 16384 + hw) * 256 + c4);
    uint lo = (uint)f2bf(v4.x) | ((uint)f2bf(v4.y) << 16);
    uint hi = (uint)f2bf(v4.z) | ((uint)f2bf(v4.w) << 16);
    u32x2 pk = {lo, hi};
    *(u32x2*)(xc + (size_t)row * 256 + c4) = pk;
  }
}

// ---------------------------------------------------------------- tiled GEMM (m97 structure + XCD swizzle)
template<int N>
__global__ __launch_bounds__(256) void k_gemm2(const ushort* __restrict__ A,
    const ushort* __restrict__ W, const float* __restrict__ bias,
    ushort* __restrict__ C)
{
  constexpr int K = 256;
  __shared__ __align__(16) ushort As[2][128 * 64];
  __shared__ __align__(16) ushort Bs[2][128 * 64];
  int lin = blockIdx.y * gridDim.x + blockIdx.x;
  int qq = (gridDim.x * gridDim.y) >> 3;
  int sw2 = (lin & 7) * qq + (lin >> 3);
  int m0 = (sw2 / gridDim.x) * 128, n0 = (sw2 % gridDim.x) * 128;
  int tid = threadIdx.x, lane = tid & 63;
  int wave = tid >> 6;
  int lm = lane & 15, kg = lane >> 4;
  int wr = wave >> 1, wc = wave & 1;

  const char* Ab = (const char*)A + (size_t)m0 * (K * 2);
  const char* Bb = (const char*)W + (size_t)n0 * (K * 2);

  auto stage = [&](int buf, int kt) {
#pragma unroll
    for (int j = 0; j < 4; ++j) {
      int c = j * 256 + tid;            // chunk 0..1023
      int row = c >> 3, slot = c & 7;   // 8 x 16B per 128B row
      int srcoff = row * (K * 2) + kt * 128 + ((slot * 16) ^ ((row & 7) << 4));
      gl16(Ab + srcoff, (const ushort*)((const char*)As[buf] + c * 16));
      gl16(Bb + srcoff, (const ushort*)((const char*)Bs[buf] + c * 16));
    }
  };

  f32x4 acc[4][4];
  f32x4 zero = {0.f, 0.f, 0.f, 0.f};
#pragma unroll
  for (int a = 0; a < 4; ++a)
#pragma unroll
    for (int b = 0; b < 4; ++b) acc[a][b] = zero;

  stage(0, 0);
  __syncthreads();
#pragma unroll
  for (int t = 0; t < 4; ++t) {
    int cur = t & 1;
    if (t < 3) stage(cur ^ 1, t + 1);
#pragma unroll
    for (int s = 0; s < 2; ++s) {
      int sw = (lm & 7) << 4;
      bf16x8 af[4], bw[4];
#pragma unroll
      for (int mi = 0; mi < 4; ++mi) {
        int row = wr * 64 + mi * 16 + lm;
        af[mi] = *(const bf16x8*)((const char*)As[cur] + row * 128 + ((s * 64 + kg * 16) ^ sw));
      }
#pragma unroll
      for (int ni = 0; ni < 4; ++ni) {
        int row = wc * 64 + ni * 16 + lm;
        bw[ni] = *(const bf16x8*)((const char*)Bs[cur] + row * 128 + ((s * 64 + kg * 16) ^ sw));
      }
#pragma unroll
      for (int mi = 0; mi < 4; ++mi)
#pragma unroll
        for (int ni = 0; ni < 4; ++ni)
          acc[mi][ni] = __builtin_amdgcn_mfma_f32_16x16x32_bf16(af[mi], bw[ni], acc[mi][ni], 0, 0, 0);
    }
    __syncthreads();
  }

  int rbase = m0 + wr * 64 + kg * 4;
#pragma unroll
  for (int ni = 0; ni < 4; ++ni) {
    int col = n0 + wc * 64 + ni * 16 + lm;
    float bv = bias[col];
#pragma unroll
    for (int mi = 0; mi < 4; ++mi) {
#pragma unroll
      for (int r = 0; r < 4; ++r)
        C[(size_t)(rbase + mi * 16 + r) * N + col] = f2bf(acc[mi][ni][r] + bv);
    }
  }
}

// ---------------------------------------------------------------- proj GEMM with fused scatter epilogue
__global__ __launch_bounds__(256) void k_gemm_out(const ushort* __restrict__ A,
    const ushort* __restrict__ W, const float* __restrict__ bias,
    float* __restrict__ out)
{
  constexpr int K = 256;
  __shared__ __align__(16) ushort As[2][128 * 64];
  __shared__ __align__(16) ushort Bs[2][128 * 64];
  int lin = blockIdx.y * gridDim.x + blockIdx.x;
  int qq = (gridDim.x * gridDim.y) >> 3;
  int sw2 = (lin & 7) * qq + (lin >> 3);
  int m0 = (sw2 / gridDim.x) * 128, n0 = (sw2 % gridDim.x) * 128;
  int tid = threadIdx.x, lane = tid & 63;
  int wave = tid >> 6;
  int lm = lane & 15, kg = lane >> 4;
  int wr = wave >> 1, wc = wave & 1;

  const char* Ab = (const char*)A + (size_t)m0 * (K * 2);
  const char* Bb = (const char*)W + (size_t)n0 * (K * 2);

  auto stage = [&](int buf, int kt) {
#pragma unroll
    for (int j = 0; j < 4; ++j) {
      int c = j * 256 + tid;
      int row = c >> 3, slot = c & 7;
      int srcoff = row * (K * 2) + kt * 128 + ((slot * 16) ^ ((row & 7) << 4));
      gl16(Ab + srcoff, (const ushort*)((const char*)As[buf] + c * 16));
      gl16(Bb + srcoff, (const ushort*)((const char*)Bs[buf] + c * 16));
    }
  };

  f32x4 acc[4][4];
  f32x4 zero = {0.f, 0.f, 0.f, 0.f};
#pragma unroll
  for (int a = 0; a < 4; ++a)
#pragma unroll
    for (int b = 0; b < 4; ++b) acc[a][b] = zero;

  stage(0, 0);
  __syncthreads();
#pragma unroll
  for (int t = 0; t < 4; ++t) {
    int cur = t & 1;
    if (t < 3) stage(cur ^ 1, t + 1);
#pragma unroll
    for (int s = 0; s < 2; ++s) {
      int sw = (lm & 7) << 4;
      bf16x8 af[4], bw[4];
#pragma unroll
      for (int mi = 0; mi < 4; ++mi) {
        int row = wr * 64 + mi * 16 + lm;
        af[mi] = *(const bf16x8*)((const char*)As[cur] + row * 128 + ((s * 64 + kg * 16) ^ sw));
      }
#pragma unroll
      for (int ni = 0; ni < 4; ++ni) {
        int row = wc * 64 + ni * 16 + lm;
        bw[ni] = *(const bf16x8*)((const char*)Bs[cur] + row * 128 + ((s * 64 + kg * 16) ^ sw));
      }
#pragma unroll
      for (int mi = 0; mi < 4; ++mi)
#pragma unroll
        for (int ni = 0; ni < 4; ++ni)
          acc[mi][ni] = __builtin_amdgcn_mfma_f32_16x16x32_bf16(af[mi], bw[ni], acc[mi][ni], 0, 0, 0);
    }
    __syncthreads();
  }

  int rbase = m0 + wr * 64 + kg * 4;
#pragma unroll
  for (int mi = 0; mi < 4; ++mi) {
#pragma unroll
    for (int r = 0; r < 4; ++r) {
      int g = rbase + mi * 16 + r;
      int wi2 = g / 65;
      int n = g - wi2 * 65;
      size_t dstrow;
      if (n == 0) {
        dstrow = (size_t)(16777216 >> 8) + wi2;         // gt_out row
      } else {
        int s = n - 1;
        int b = wi2 >> 8, wh = (wi2 >> 4) & 15, ww = wi2 & 15;
        int r2 = s >> 3, cc = s & 7;
        dstrow = (size_t)(b << 14) + (wh * 8 + r2) * 128 + ww * 8 + cc;
      }
      float* dst = out + dstrow * 256;
#pragma unroll
      for (int ni = 0; ni < 4; ++ni) {
        int col = n0 + wc * 64 + ni * 16 + lm;
        dst[col] = acc[mi][ni][r] + bias[col];
      }
    }
  }
}

// ---------------------------------------------------------------- SR conv (r6 proven version): 512 threads,
// double-buffered U, 1 barrier per tap; wave owns 64s x 32o; build spread over 16 groups.
__global__ __launch_bounds__(512) void k_conv(const ushort* __restrict__ xc,
    const ushort* __restrict__ wconv, ushort* __restrict__ cconv)
{
  __shared__ ushort U[2][64 * 256];
  int wi = blockIdx.x;
  int tid = threadIdx.x, wave = tid >> 6, lane = tid & 63;
  int lm = lane & 15, kg = lane >> 4;
  const ushort* src = xc + (size_t)(wi * 65 + 1) * 256;
  f32x4 acc[4][2];
  f32x4 zero = {0.f, 0.f, 0.f, 0.f};
#pragma unroll
  for (int a = 0; a < 4; a++)
#pragma unroll
    for (int b = 0; b < 2; b++) acc[a][b] = zero;

  int cb = (tid & 31) * 8;   // channel block (8 ch)
  int sg = tid >> 5;         // spatial group 0..15

  auto build = [&](int t, ushort* Ub) {
    int dy = t >> 1, dx = t & 1;
    for (int s = sg; s < 64; s += 16) {
      int i = s >> 3, j = s & 7;
      int yy = 2 * i + dy, xx = 2 * j + dx;
      float py = yy * (7.0f / 15.0f); int iy = (int)py; if (iy > 6) iy = 6; float ty = py - iy;
      float px = xx * (7.0f / 15.0f); int ix = (int)px; if (ix > 6) ix = 6; float tx = px - ix;
      float w00 = (1.f - ty) * (1.f - tx), w01 = (1.f - ty) * tx;
      float w10 = ty * (1.f - tx), w11 = ty * tx;
      const ushort* p = src + (size_t)(iy * 8 + ix) * 256 + cb;
      bf16x8 p00 = *(const bf16x8*)(p);
      bf16x8 p01 = *(const bf16x8*)(p + 256);
      bf16x8 p10 = *(const bf16x8*)(p + 2048);
      bf16x8 p11 = *(const bf16x8*)(p + 2304);
      bf16x8 o8;
#pragma unroll
      for (int jj = 0; jj < 8; jj++) {
        float v = w00 * bf2f((ushort)p00[jj]) + w01 * bf2f((ushort)p01[jj])
                + w10 * bf2f((ushort)p10[jj]) + w11 * bf2f((ushort)p11[jj]);
        o8[jj] = (short)f2bf(v);
      }
      int byteoff = s * 512 + ((2 * cb) ^ ((s & 7) << 4));
      *(bf16x8*)((char*)Ub + byteoff) = o8;
    }
  };

  build(0, U[0]);
  __syncthreads();
  for (int t = 0; t < 4; t++) {
    const ushort* Ub = U[t & 1];
    const ushort* wc = wconv + t * 256;
    for (int kk = 0; kk < 256; kk += 32) {
      int kb = kk + kg * 8;
      bf16x8 afr[4];
#pragma unroll
      for (int mi = 0; mi < 4; mi++) {
        int srow = mi * 16 + lm;
        int off = (srow * 512 + 2 * kb) ^ ((srow & 7) << 4);
        afr[mi] = *(const bf16x8*)((const char*)Ub + off);
      }
#pragma unroll
      for (int ni = 0; ni < 2; ni++) {
        bf16x8 b = *(const bf16x8*)(wc + (size_t)(wave * 32 + ni * 16 + lm) * 1024 + kb);
#pragma unroll
        for (int mi = 0; mi < 4; mi++)
          acc[mi][ni] = __builtin_amdgcn_mfma_f32_16x16x32_bf16(afr[mi], b, acc[mi][ni], 0, 0, 0);
      }
    }
    if (t < 3) build(t + 1, U[(t + 1) & 1]);
    __syncthreads();
  }

#pragma unroll
  for (int mi = 0; mi < 4; mi++) {
    int row = wi * 64 + mi * 16 + kg * 4;
#pragma unroll
    for (int ni = 0; ni < 2; ni++) {
      int col = wave * 32 + ni * 16 + lm;
#pragma unroll
      for (int r = 0; r < 4; r++)
        cconv[(size_t)(row + r) * 256 + col] = f2bf(acc[mi][ni][r]);
    }
  }
}

// ---------------------------------------------------------------- bias + LayerNorm (vectorized loads) -> xkv rows 1..64
__global__ __launch_bounds__(256) void k_ln(const ushort* __restrict__ cconv,
    const float* __restrict__ srb, const float* __restrict__ nw,
    const float* __restrict__ nb, ushort* __restrict__ xkv)
{
  int row = blockIdx.x * 4 + (threadIdx.x >> 6);   // 0..65535
  int lane = threadIdx.x & 63;
  int c0 = lane * 4;                               // 4 contiguous channels/thread
  u32x2 pk = *(const u32x2*)(cconv + (size_t)row * 256 + c0);
  float4 sb4 = *(const float4*)(srb + c0);
  float v0 = bf2f((ushort)(pk.x & 0xffffu)) + sb4.x;
  float v1 = bf2f((ushort)(pk.x >> 16))     + sb4.y;
  float v2 = bf2f((ushort)(pk.y & 0xffffu)) + sb4.z;
  float v3 = bf2f((ushort)(pk.y >> 16))     + sb4.w;
  float sum = v0 + v1 + v2 + v3;
  float sq  = v0 * v0 + v1 * v1 + v2 * v2 + v3 * v3;
#pragma unroll
  for (int off = 1; off < 64; off <<= 1) {
    sum += __shfl_xor(sum, off, 64);
    sq  += __shfl_xor(sq,  off, 64);
  }
  float mean = sum * (1.f / 256.f);
  float var = sq * (1.f / 256.f) - mean * mean;
  float rs = rsqrtf(var + 1e-5f);
  float4 nw4 = *(const float4*)(nw + c0);
  float4 nb4 = *(const float4*)(nb + c0);
  int wi = row >> 6, s = row & 63;
  ushort* o = xkv + (size_t)(wi * 65 + 1 + s) * 256 + c0;
  uint lo = (uint)f2bf((v0 - mean) * rs * nw4.x + nb4.x)
          | ((uint)f2bf((v1 - mean) * rs * nw4.y + nb4.y) << 16);
  uint hi = (uint)f2bf((v2 - mean) * rs * nw4.z + nb4.z)
          | ((uint)f2bf((v3 - mean) * rs * nw4.w + nb4.w) << 16);
  u32x2 opk = {lo, hi};
  *(u32x2*)o = opk;
}

// ---------------------------------------------------------------- MFMA attention: one wave per (window, head)
__global__ __launch_bounds__(256) void k_attn(const ushort* __restrict__ q,
    const ushort* __restrict__ kv, ushort* __restrict__ att)
{
  __shared__ ushort smem[4][8064];           // per wave: P [80][72] + V^T [32][72]
  int wi = blockIdx.x >> 1;
  int tid = threadIdx.x, wave = tid >> 6, lane = tid & 63;
  int h = (blockIdx.x & 1) * 4 + wave;
  int lm = lane & 15, kg = lane >> 4;
  ushort* plds = smem[wave];                 // [80][72] bf16 P (later reused for O)
  ushort* vt   = smem[wave] + 5760;          // [32][72] bf16 V^T

  size_t qbase  = (size_t)wi * 65 * 256 + (size_t)h * 32;
  size_t kvbase = (size_t)wi * 65 * 512 + (size_t)h * 32;

  for (int e = lane; e < 2080; e += 64) {
    int m = e >> 5, d = e & 31;
    vt[d * 72 + m] = kv[kvbase + (size_t)m * 512 + 256 + d];
  }

  bf16x8 akf[5], bqf[5];
#pragma unroll
  for (int i = 0; i < 5; i++) {
    akf[i] = *(const bf16x8*)(kv + kvbase + (size_t)(16 * i + lm) * 512 + kg * 8);
    bqf[i] = *(const bf16x8*)(q  + qbase  + (size_t)(16 * i + lm) * 256 + kg * 8);
  }

  f32x4 sc[5][5];
  f32x4 zero = {0.f, 0.f, 0.f, 0.f};
#pragma unroll
  for (int mi = 0; mi < 5; mi++)
#pragma unroll
    for (int nj = 0; nj < 5; nj++) sc[mi][nj] = zero;
#pragma unroll
  for (int mi = 0; mi < 5; mi++)
#pragma unroll
    for (int nj = 0; nj < 5; nj++)
      sc[mi][nj] = __builtin_amdgcn_mfma_f32_16x16x32_bf16(akf[mi], bqf[nj], sc[mi][nj], 0, 0, 0);

  const float C = SCALE_ * 1.4426950408889634f;   // scale * log2(e)
  float inv[5], p64b[5];
#pragma unroll
  for (int nj = 0; nj < 5; nj++) {
    float s4 = sc[4][nj][0];                      // m = 64+4*kg; valid only kg==0
    float mx = (kg == 0) ? s4 : -1e30f;
#pragma unroll
    for (int mi = 0; mi < 4; mi++)
#pragma unroll
      for (int r = 0; r < 4; r++) mx = fmaxf(mx, sc[mi][nj][r]);
    mx = fmaxf(mx, __shfl_xor(mx, 16, 64));
    mx = fmaxf(mx, __shfl_xor(mx, 32, 64));
    float sum = 0.f;
#pragma unroll
    for (int mi = 0; mi < 4; mi++)
#pragma unroll
      for (int r = 0; r < 4; r++) {
        float e = exp2f((sc[mi][nj][r] - mx) * C);
        sc[mi][nj][r] = e; sum += e;
      }
    float e4 = exp2f((s4 - mx) * C);
    sum += (kg == 0) ? e4 : 0.f;
    sum += __shfl_xor(sum, 16, 64);
    sum += __shfl_xor(sum, 32, 64);
    inv[nj] = 1.0f / sum;
    p64b[nj] = __shfl(e4, lm, 64);                // broadcast kg==0 value
  }

#pragma unroll
  for (int nj = 0; nj < 5; nj++) {
    int n = 16 * nj + lm;
#pragma unroll
    for (int mi = 0; mi < 4; mi++) {
      uint lo = (uint)f2bf(sc[mi][nj][0]) | ((uint)f2bf(sc[mi][nj][1]) << 16);
      uint hi = (uint)f2bf(sc[mi][nj][2]) | ((uint)f2bf(sc[mi][nj][3]) << 16);
      u32x2 pk = {lo, hi};
      *(u32x2*)(plds + n * 72 + 16 * mi + 4 * kg) = pk;
    }
  }

  f32x4 od[2][5];
#pragma unroll
  for (int dt = 0; dt < 2; dt++)
#pragma unroll
    for (int nj = 0; nj < 5; nj++) od[dt][nj] = zero;
#pragma unroll
  for (int c = 0; c < 2; c++) {
    bf16x8 av[2], bp[5];
#pragma unroll
    for (int dt = 0; dt < 2; dt++)
      av[dt] = *(const bf16x8*)(vt + (16 * dt + lm) * 72 + c * 32 + kg * 8);
#pragma unroll
    for (int nj = 0; nj < 5; nj++)
      bp[nj] = *(const bf16x8*)(plds + (16 * nj + lm) * 72 + c * 32 + kg * 8);
#pragma unroll
    for (int dt = 0; dt < 2; dt++)
#pragma unroll
      for (int nj = 0; nj < 5; nj++)
        od[dt][nj] = __builtin_amdgcn_mfma_f32_16x16x32_bf16(av[dt], bp[nj], od[dt][nj], 0, 0, 0);
  }
  float v64[8];
#pragma unroll
  for (int dt = 0; dt < 2; dt++)
#pragma unroll
    for (int r = 0; r < 4; r++)
      v64[dt * 4 + r] = bf2f(vt[(16 * dt + 4 * kg + r) * 72 + 64]);
#pragma unroll
  for (int dt = 0; dt < 2; dt++)
#pragma unroll
    for (int nj = 0; nj < 5; nj++)
#pragma unroll
      for (int r = 0; r < 4; r++)
        od[dt][nj][r] += v64[dt * 4 + r] * p64b[nj];

#pragma unroll
  for (int nj = 0; nj < 5; nj++) {
    int n = 16 * nj + lm;
    float scl = inv[nj];
#pragma unroll
    for (int dt = 0; dt < 2; dt++) {
      uint lo = (uint)f2bf(od[dt][nj][0] * scl) | ((uint)f2bf(od[dt][nj][1] * scl) << 16);
      uint hi = (uint)f2bf(od[dt][nj][2] * scl) | ((uint)f2bf(od[dt][nj][3] * scl) << 16);
      u32x2 pk = {lo, hi};
      *(u32x2*)(plds + n * 40 + 16 * dt + 4 * kg) = pk;
    }
  }
  size_t abase = (size_t)wi * 65 * 256 + (size_t)h * 32;
  for (int e = lane; e < 1040; e += 64) {
    int n = e >> 4, d2 = e & 15;
    *(uint*)(att + abase + (size_t)n * 256 + 2 * d2) = *(const uint*)(plds + n * 40 + 2 * d2);
  }
}

// ---------------------------------------------------------------- launch
extern "C" void kernel_launch(void* const* d_in, const int* in_sizes, int n_in,
                              void* d_out, int out_size, void* d_ws, size_t ws_size,
                              hipStream_t stream)
{
  const float* x    = (const float*)d_in[0];
  const float* gt   = (const float*)d_in[1];
  const float* q_w  = (const float*)d_in[2];
  const float* q_b  = (const float*)d_in[3];
  const float* kv_w = (const float*)d_in[4];
  const float* kv_b = (const float*)d_in[5];
  const float* sr_w = (const float*)d_in[6];
  const float* sr_b = (const float*)d_in[7];
  const float* nw   = (const float*)d_in[8];
  const float* nb   = (const float*)d_in[9];
  const float* p_w  = (const float*)d_in[10];
  const float* p_b  = (const float*)d_in[11];
  (void)in_sizes; (void)n_in; (void)out_size;

  if (ws_size < 204996608u) return;
  char* ws = (char*)d_ws;
  ushort* xc  = (ushort*)(ws);              // 34,078,720  (reused as att out)
  ushort* qb  = (ushort*)(ws + 34078720);   // 34,078,720  (Q-proj output)
  ushort* xkv = (ushort*)(ws + 68157440);   // 34,078,720
  ushort* kv  = (ushort*)(ws + 102236160);  // 68,157,440
  ushort* ccv = (ushort*)(ws + 170393600);  // 33,554,432
  ushort* wq  = (ushort*)(ws + 203948032);  // 131,072
  ushort* wkv = (ushort*)(ws + 204079104);  // 262,144
  ushort* wpr = (ushort*)(ws + 204341248);  // 131,072
  ushort* wcv = (ushort*)(ws + 204472320);  // 524,288

  float* out = (float*)d_out;
  float* out2 = out + 16777216 + 262144;    // skip

  k_prep<<<18688, 256, 0, stream>>>(x, gt, q_w, kv_w, p_w, sr_w,
                                    xc, xkv, out2, wq, wkv, wpr, wcv);
  k_gemm2<256><<<dim3(2, 520), 256, 0, stream>>>(xc, wq, q_b, qb);
  k_conv<<<1024, 512, 0, stream>>>(xc, wcv, ccv);
  k_ln<<<16384, 256, 0, stream>>>(ccv, sr_b, nw, nb, xkv);
  k_gemm2<512><<<dim3(4, 520), 256, 0, stream>>>(xkv, wkv, kv_b, kv);
  k_attn<<<2048, 256, 0, stream>>>(qb, kv, xc);
  k_gemm_out<<<dim3(2, 520), 256, 0, stream>>>(xc, wpr, p_b, out);
}